// Round 1
// baseline (155.028 us; speedup 1.0000x reference)
//
#include <hip/hip_runtime.h>

// ============================================================================
// ESupConLoss on MI355X (gfx950)
//
// out = ( pt_loss + sum_i[ -pos_i + neg_i + 2*dot(au_i,tp_i) ] ) / (N+2)
//   pos_i = ln( sum_{j!=i} e^{au_i.au_j} + e^{tp_i.tp_j} )
//   neg_i = ln( sum_{j!=i} e^{au_i.tp_j} )
//   pt_loss = (sum_i au_i - sum_i tp_i) . (pt1 - pt0) / N
//
// Trick: pre-scale inputs by sqrt(log2 e) and cast to bf16; then every MFMA
// dot product is already in log2 domain, v_exp_f32 (=2^x) needs no scaling,
// and the fixed shift C=32 (folded into the MFMA C-init) cancels in -pos+neg.
// No online max needed: |logit| <= ~70*log2e ~ 101, 2^(101-32)*16384 < f32 max.
// ============================================================================

typedef float f32x4 __attribute__((ext_vector_type(4)));
typedef __bf16 bf16x8 __attribute__((ext_vector_type(8)));

static constexpr int   N_ROWS = 8192;
static constexpr int   DIM    = 128;
static constexpr float SQRT_LOG2E = 1.2011224087864498f; // sqrt(log2(e))
static constexpr float C2  = 32.0f;                      // log2-domain shift
static constexpr float LN2 = 0.6931471805599453f;

// ---------------- ws layout (bytes) ----------------
// zb_au : bf16[8192*128]  @ 0          (2 MiB)
// zb_tp : bf16[8192*128]  @ 2097152    (2 MiB)
// P     : f32[8192]       @ 4194304    (pos exp-sums)
// Ng    : f32[8192]       @ 4227072    (neg exp-sums)
// acc   : f32[2]          @ 4259840    (acc[0]=supcon, acc[1]=pt numerator)

__device__ inline unsigned short f2bf_rne(float x) {
    unsigned u = __builtin_bit_cast(unsigned, x);
    u += 0x7fffu + ((u >> 16) & 1u);
    return (unsigned short)(u >> 16);
}

// ---------------------------------------------------------------------------
// Kernel 1: convert f32 -> bf16 (scaled), zero P/Ng/acc.
// grid 1024 x 256, 4 elems/thread/array.
// ---------------------------------------------------------------------------
__global__ void prep_kernel(const float* __restrict__ zau,
                            const float* __restrict__ ztp,
                            unsigned short* __restrict__ bau,
                            unsigned short* __restrict__ btp,
                            float* __restrict__ P, float* __restrict__ Ng,
                            float* __restrict__ acc) {
    int gid  = blockIdx.x * blockDim.x + threadIdx.x;   // 0..262143
    int base = gid * 4;
    float4 a = *reinterpret_cast<const float4*>(zau + base);
    float4 t = *reinterpret_cast<const float4*>(ztp + base);
    ushort4 ua, ut;
    ua.x = f2bf_rne(a.x * SQRT_LOG2E); ua.y = f2bf_rne(a.y * SQRT_LOG2E);
    ua.z = f2bf_rne(a.z * SQRT_LOG2E); ua.w = f2bf_rne(a.w * SQRT_LOG2E);
    ut.x = f2bf_rne(t.x * SQRT_LOG2E); ut.y = f2bf_rne(t.y * SQRT_LOG2E);
    ut.z = f2bf_rne(t.z * SQRT_LOG2E); ut.w = f2bf_rne(t.w * SQRT_LOG2E);
    *reinterpret_cast<ushort4*>(bau + base) = ua;
    *reinterpret_cast<ushort4*>(btp + base) = ut;
    if (gid < N_ROWS) { P[gid] = 0.0f; Ng[gid] = 0.0f; }
    if (gid == 0)     { acc[0] = 0.0f; acc[1] = 0.0f; }
}

// ---------------------------------------------------------------------------
// Kernel 2: the three similarity matrices -> per-row exp-sums.
// 512 blocks = 64 row-tiles (128 rows) x 8 column-splits (1024 cols each).
// Block = 4 waves, wave owns 32 rows (2 m-tiles). Col tiles of 64 staged in
// LDS (row stride 136 ushorts = 272 B -> conflict-free b128 phases).
// MFMA 16x16x32 bf16 layouts (HW-verified):
//   A/B frag: elem j of lane -> index (lane&15), k = (lane>>4)*8 + j
//   C/D     : reg r of lane  -> row (lane>>4)*4 + r, col (lane&15)
// ---------------------------------------------------------------------------
template<bool DIAG>
__device__ inline void accum_exp(const f32x4 (&acc)[2][4], float (&dst)[2][4],
                                 int r0w, int colbase, int quad, int l15) {
#pragma unroll
    for (int mt = 0; mt < 2; mt++)
#pragma unroll
        for (int nt = 0; nt < 4; nt++)
#pragma unroll
            for (int r = 0; r < 4; r++) {
                float e = __builtin_amdgcn_exp2f(acc[mt][nt][r]);
                if (DIAG) {
                    int grow = r0w + mt * 16 + quad * 4 + r;
                    int gcol = colbase + nt * 16 + l15;
                    if (grow == gcol) e = 0.0f;
                }
                dst[mt][r] += e;
            }
}

__global__ __launch_bounds__(256, 2)
void score_kernel(const unsigned short* __restrict__ bau,
                  const unsigned short* __restrict__ btp,
                  float* __restrict__ P, float* __restrict__ Ng) {
    __shared__ __align__(16) unsigned short ldsA[64 * 136];
    __shared__ __align__(16) unsigned short ldsT[64 * 136];

    const int tid  = threadIdx.x;
    const int lane = tid & 63;
    const int wave = tid >> 6;
    const int quad = lane >> 4;
    const int l15  = lane & 15;
    const int rb   = blockIdx.x >> 3;   // row tile 0..63
    const int cs   = blockIdx.x & 7;    // col split 0..7
    const int r0w  = rb * 128 + wave * 32;

    // loop-invariant A fragments (rows of au / tp), 64 VGPRs total
    bf16x8 aAu[2][4], aTp[2][4];
#pragma unroll
    for (int mt = 0; mt < 2; mt++) {
        int row = r0w + mt * 16 + l15;
        const unsigned short* pa = bau + row * DIM + quad * 8;
        const unsigned short* pt = btp + row * DIM + quad * 8;
#pragma unroll
        for (int k = 0; k < 4; k++) {
            aAu[mt][k] = *reinterpret_cast<const bf16x8*>(pa + k * 32);
            aTp[mt][k] = *reinterpret_cast<const bf16x8*>(pt + k * 32);
        }
    }

    float sP[2][4] = {{0.f,0.f,0.f,0.f},{0.f,0.f,0.f,0.f}};
    float sN[2][4] = {{0.f,0.f,0.f,0.f},{0.f,0.f,0.f,0.f}};

    for (int ct = 0; ct < 16; ct++) {
        const int colbase = cs * 1024 + ct * 64;
        __syncthreads();
        // ---- stage 64x128 bf16 of au and tp into padded LDS ----
#pragma unroll
        for (int j = 0; j < 8; j++) {
            int c   = tid + j * 256;      // 0..2047 chunks of 16B
            int arr = c >> 10;
            int rem = c & 1023;
            int row = rem >> 4;
            int c16 = rem & 15;
            const unsigned short* src =
                (arr ? btp : bau) + (colbase + row) * DIM + c16 * 8;
            unsigned short* dst = (arr ? ldsT : ldsA) + row * 136 + c16 * 8;
            *reinterpret_cast<bf16x8*>(dst) =
                *reinterpret_cast<const bf16x8*>(src);
        }
        __syncthreads();

        const bool diag = (colbase < r0w + 32) && (colbase + 64 > r0w);

        // ---- pass 1: s_aa (A = au rows, B = au cols) ----
        {
            f32x4 acc[2][4];
#pragma unroll
            for (int mt = 0; mt < 2; mt++)
#pragma unroll
                for (int nt = 0; nt < 4; nt++)
                    acc[mt][nt] = f32x4{-C2, -C2, -C2, -C2};
#pragma unroll
            for (int k = 0; k < 4; k++) {
                bf16x8 b[4];
#pragma unroll
                for (int nt = 0; nt < 4; nt++)
                    b[nt] = *reinterpret_cast<const bf16x8*>(
                        ldsA + (nt * 16 + l15) * 136 + k * 32 + quad * 8);
#pragma unroll
                for (int nt = 0; nt < 4; nt++)
#pragma unroll
                    for (int mt = 0; mt < 2; mt++)
                        acc[mt][nt] = __builtin_amdgcn_mfma_f32_16x16x32_bf16(
                            aAu[mt][k], b[nt], acc[mt][nt], 0, 0, 0);
            }
            if (diag) accum_exp<true >(acc, sP, r0w, colbase, quad, l15);
            else      accum_exp<false>(acc, sP, r0w, colbase, quad, l15);
        }

        // ---- pass 2: s_tt and s_at share the tp B-fragments ----
        {
            f32x4 accT[2][4], accX[2][4];
#pragma unroll
            for (int mt = 0; mt < 2; mt++)
#pragma unroll
                for (int nt = 0; nt < 4; nt++) {
                    accT[mt][nt] = f32x4{-C2, -C2, -C2, -C2};
                    accX[mt][nt] = f32x4{-C2, -C2, -C2, -C2};
                }
#pragma unroll
            for (int k = 0; k < 4; k++) {
                bf16x8 b[4];
#pragma unroll
                for (int nt = 0; nt < 4; nt++)
                    b[nt] = *reinterpret_cast<const bf16x8*>(
                        ldsT + (nt * 16 + l15) * 136 + k * 32 + quad * 8);
#pragma unroll
                for (int nt = 0; nt < 4; nt++)
#pragma unroll
                    for (int mt = 0; mt < 2; mt++) {
                        accT[mt][nt] = __builtin_amdgcn_mfma_f32_16x16x32_bf16(
                            aTp[mt][k], b[nt], accT[mt][nt], 0, 0, 0);
                        accX[mt][nt] = __builtin_amdgcn_mfma_f32_16x16x32_bf16(
                            aAu[mt][k], b[nt], accX[mt][nt], 0, 0, 0);
                    }
            }
            if (diag) { accum_exp<true >(accT, sP, r0w, colbase, quad, l15);
                        accum_exp<true >(accX, sN, r0w, colbase, quad, l15); }
            else      { accum_exp<false>(accT, sP, r0w, colbase, quad, l15);
                        accum_exp<false>(accX, sN, r0w, colbase, quad, l15); }
        }
    }

    // ---- reduce across the 16 lanes of each quad, one atomic per row ----
#pragma unroll
    for (int mt = 0; mt < 2; mt++)
#pragma unroll
        for (int r = 0; r < 4; r++) {
            float p = sP[mt][r], ng = sN[mt][r];
            for (int m = 1; m < 16; m <<= 1) {
                p  += __shfl_xor(p,  m, 64);
                ng += __shfl_xor(ng, m, 64);
            }
            if (l15 == 0) {
                int row = r0w + mt * 16 + quad * 4 + r;
                atomicAdd(&P[row],  p);
                atomicAdd(&Ng[row], ng);
            }
        }
}

// ---------------------------------------------------------------------------
// Kernel 3: per-row  ln2*(log2 Ng - log2 P) + 2*dot(au_i,tp_i), plus the
// pt numerator sum_i (au_i - tp_i).(pt1-pt0). One wave per 8 rows.
// ---------------------------------------------------------------------------
__global__ void finalize_kernel(const float* __restrict__ zau,
                                const float* __restrict__ ztp,
                                const float* __restrict__ fc,
                                const float* __restrict__ P,
                                const float* __restrict__ Ng,
                                float* __restrict__ acc) {
    int tid     = threadIdx.x;
    int lane    = tid & 63;
    int wave_id = blockIdx.x * 4 + (tid >> 6);   // 0..1023

    float2 w0 = *reinterpret_cast<const float2*>(fc + 2 * lane);        // pt0
    float2 w1 = *reinterpret_cast<const float2*>(fc + 256 + 2 * lane);  // pt1
    float wx = w1.x - w0.x, wy = w1.y - w0.y;

    float ptp = 0.0f, ssum = 0.0f;
    for (int j = 0; j < 8; j++) {
        int i = wave_id * 8 + j;
        float2 a = *reinterpret_cast<const float2*>(zau + i * DIM + 2 * lane);
        float2 t = *reinterpret_cast<const float2*>(ztp + i * DIM + 2 * lane);
        float d = a.x * t.x + a.y * t.y;
        ptp += (a.x - t.x) * wx + (a.y - t.y) * wy;
        for (int m = 1; m < 64; m <<= 1) d += __shfl_xor(d, m, 64);
        if (lane == 0) {
            float c = LN2 * (__builtin_amdgcn_logf(Ng[i]) -
                             __builtin_amdgcn_logf(P[i])) + 2.0f * d;
            ssum += c;
        }
    }
    for (int m = 1; m < 64; m <<= 1) ptp += __shfl_xor(ptp, m, 64);
    if (lane == 0) {
        atomicAdd(&acc[0], ssum);
        atomicAdd(&acc[1], ptp);
    }
}

// ---------------------------------------------------------------------------
// Kernel 4: final scalar.
// ---------------------------------------------------------------------------
__global__ void write_out_kernel(const float* __restrict__ acc,
                                 float* __restrict__ out) {
    out[0] = (acc[1] / (float)N_ROWS + acc[0]) / (float)(N_ROWS + 2);
}

extern "C" void kernel_launch(void* const* d_in, const int* in_sizes, int n_in,
                              void* d_out, int out_size, void* d_ws, size_t ws_size,
                              hipStream_t stream) {
    const float* zau = (const float*)d_in[0];
    const float* ztp = (const float*)d_in[1];
    const float* fc  = (const float*)d_in[2];
    // d_in[3] = labels (unused by the math)
    float* out = (float*)d_out;

    char* ws = (char*)d_ws;
    unsigned short* bau = (unsigned short*)(ws);
    unsigned short* btp = (unsigned short*)(ws + 2097152);
    float* P   = (float*)(ws + 4194304);
    float* Ng  = (float*)(ws + 4227072);
    float* acc = (float*)(ws + 4259840);

    prep_kernel<<<dim3(1024), dim3(256), 0, stream>>>(zau, ztp, bau, btp, P, Ng, acc);
    score_kernel<<<dim3(512), dim3(256), 0, stream>>>(bau, btp, P, Ng);
    finalize_kernel<<<dim3(256), dim3(256), 0, stream>>>(zau, ztp, fc, P, Ng, acc);
    write_out_kernel<<<dim3(1), dim3(1), 0, stream>>>(acc, out);
}